// Round 1
// baseline (298.899 us; speedup 1.0000x reference)
//
#include <hip/hip_runtime.h>

typedef unsigned short u16;
typedef __bf16 bf16x8 __attribute__((ext_vector_type(8)));
typedef float f32x4 __attribute__((ext_vector_type(4)));

__device__ __forceinline__ u16 f2b(float f) {
    unsigned int u = __float_as_uint(f);
    u += 0x7fffu + ((u >> 16) & 1u);
    return (u16)(u >> 16);
}

// ---------------- pack x: NHWC fp32 -> patch-order bf16 ----------------
// out row m = b*144 + (y/7)*12 + (x/7); within row k = ((y%7)*7 + x%7)*256 + c
__global__ __launch_bounds__(256) void k_pack_x(const float* __restrict__ x,
                                                u16* __restrict__ xp) {
    int v = blockIdx.x * 256 + threadIdx.x;      // 1,806,336 total
    int c0 = (v & 31) << 3;                      // 8-channel chunk
    int pix = v >> 5;                            // 0..56447
    int b = pix / 7056;
    int r = pix - b * 7056;
    int y = r / 84;
    int xx = r - y * 84;
    int opix = (b * 144 + (y / 7) * 12 + (xx / 7)) * 49 + (y % 7) * 7 + (xx % 7);
    const float4* src = reinterpret_cast<const float4*>(x + ((size_t)pix << 8) + c0);
    float4 f0 = src[0], f1 = src[1];
    uint4 o;
    o.x = (unsigned)f2b(f0.x) | ((unsigned)f2b(f0.y) << 16);
    o.y = (unsigned)f2b(f0.z) | ((unsigned)f2b(f0.w) << 16);
    o.z = (unsigned)f2b(f1.x) | ((unsigned)f2b(f1.y) << 16);
    o.w = (unsigned)f2b(f1.z) | ((unsigned)f2b(f1.w) << 16);
    *reinterpret_cast<uint4*>(xp + ((size_t)opix << 8) + c0) = o;
}

// ---------------- transpose + convert: [R][C] fp32 -> [C][R] bf16 ----------------
__global__ __launch_bounds__(256) void k_tconv(const float* __restrict__ in,
                                               u16* __restrict__ out, int R, int C) {
    __shared__ float tile[32][33];
    int c0 = blockIdx.x << 5, r0 = blockIdx.y << 5;
    int tx = threadIdx.x, ty = threadIdx.y;  // 32 x 8
#pragma unroll
    for (int i = 0; i < 4; i++)
        tile[ty + (i << 3)][tx] = in[(size_t)(r0 + ty + (i << 3)) * C + c0 + tx];
    __syncthreads();
#pragma unroll
    for (int i = 0; i < 4; i++)
        out[(size_t)(c0 + ty + (i << 3)) * R + r0 + tx] = f2b(tile[tx][ty + (i << 3)]);
}

// ---------------- kv-proj GEMM: [1152,12544] @ [12544,1024], split-K=7 ----------------
__global__ __launch_bounds__(256) void k_kvproj(const u16* __restrict__ xp,
                                                const u16* __restrict__ wkvT,
                                                float* __restrict__ parts) {
    __shared__ u16 As[128][72];
    __shared__ u16 Bs[128][72];
    const int mt = blockIdx.x, nt = blockIdx.y, sp = blockIdx.z;
    const int tid = threadIdx.x;
    const int wave = tid >> 6, lane = tid & 63;
    const int wr = wave >> 1, wc = wave & 1;
    const int lrow = lane & 15, lkg = lane >> 4;
    const u16* Ag = xp + (size_t)(mt * 128) * 12544 + sp * 1792;
    const u16* Bg = wkvT + (size_t)(nt * 128) * 12544 + sp * 1792;
    const int srow = tid >> 3, scol = (tid & 7) << 3;
    f32x4 acc[4][4];
#pragma unroll
    for (int m = 0; m < 4; m++)
#pragma unroll
        for (int n = 0; n < 4; n++)
#pragma unroll
            for (int i = 0; i < 4; i++) acc[m][n][i] = 0.f;

    for (int ks = 0; ks < 28; ks++) {
        const int k0 = ks * 64;
        __syncthreads();
#pragma unroll
        for (int p = 0; p < 4; p++) {
            int rr = srow + (p << 5);
            *reinterpret_cast<bf16x8*>(&As[rr][scol]) =
                *reinterpret_cast<const bf16x8*>(Ag + (size_t)rr * 12544 + k0 + scol);
            *reinterpret_cast<bf16x8*>(&Bs[rr][scol]) =
                *reinterpret_cast<const bf16x8*>(Bg + (size_t)rr * 12544 + k0 + scol);
        }
        __syncthreads();
#pragma unroll
        for (int kk = 0; kk < 2; kk++) {
            const int ko = (kk << 5) + (lkg << 3);
            bf16x8 a[4], bb[4];
#pragma unroll
            for (int m = 0; m < 4; m++)
                a[m] = *reinterpret_cast<const bf16x8*>(&As[(wr << 6) + (m << 4) + lrow][ko]);
#pragma unroll
            for (int n = 0; n < 4; n++)
                bb[n] = *reinterpret_cast<const bf16x8*>(&Bs[(wc << 6) + (n << 4) + lrow][ko]);
#pragma unroll
            for (int m = 0; m < 4; m++)
#pragma unroll
                for (int n = 0; n < 4; n++)
                    acc[m][n] = __builtin_amdgcn_mfma_f32_16x16x32_bf16(a[m], bb[n], acc[m][n], 0, 0, 0);
        }
    }
    float* outp = parts + (size_t)sp * 1179648;
#pragma unroll
    for (int m = 0; m < 4; m++)
#pragma unroll
        for (int n = 0; n < 4; n++)
#pragma unroll
            for (int i = 0; i < 4; i++) {
                int row = (mt << 7) + (wr << 6) + (m << 4) + (lkg << 2) + i;
                int col = (nt << 7) + (wc << 6) + (n << 4) + lrow;
                outp[(size_t)row * 1024 + col] = acc[m][n][i];
            }
}

// ---------------- reduce split-K partials -> K bf16 [bh][144][64], V^T bf16 [bh][64][160] ----------------
__global__ __launch_bounds__(256) void k_kvfin(const float* __restrict__ parts,
                                               u16* __restrict__ Kb, u16* __restrict__ Vt) {
    int idx = blockIdx.x * 256 + threadIdx.x;  // < 1152*1024
    int m = idx >> 10, n = idx & 1023;
    float s = 0.f;
#pragma unroll
    for (int sp = 0; sp < 7; sp++) s += parts[(size_t)sp * 1179648 + idx];
    int b = m / 144, pi = m - b * 144;
    int h = (n & 511) >> 6, d = n & 63;
    int bh = (b << 3) + h;
    if (n < 512)
        Kb[((size_t)bh * 144 + pi) * 64 + d] = f2b(s);
    else
        Vt[((size_t)bh * 64 + d) * 160 + pi] = f2b(s);
}

// ---------------- fused q-proj + attention ----------------
// block = 1 wave, 48 query rows of one (b,h); K=144 keys; writes O[b,pix_raster, h*64+d]
__global__ __launch_bounds__(64) void k_attn(const u16* __restrict__ xp,
                                             const u16* __restrict__ wqT,
                                             const u16* __restrict__ Kb,
                                             const u16* __restrict__ Vt,
                                             u16* __restrict__ O) {
    __shared__ u16 smem[48 * 168];  // Q region uses stride 72; P region stride 168
    const int h = blockIdx.x, t = blockIdx.y, b = blockIdx.z;
    const int lane = threadIdx.x;
    const int lrow = lane & 15, lkg = lane >> 4;
    const int bh = (b << 3) + h;

    // ---- Q = Xtile(48x256) @ WqT(64x256)^T, scaled by 0.125 ----
    const u16* Ag = xp + ((size_t)b * 7056 + (size_t)t * 48) * 256;
    const u16* Bg = wqT + ((size_t)h * 64) * 256;
    f32x4 qa[3][4];
#pragma unroll
    for (int m = 0; m < 3; m++)
#pragma unroll
        for (int n = 0; n < 4; n++)
#pragma unroll
            for (int i = 0; i < 4; i++) qa[m][n][i] = 0.f;
#pragma unroll
    for (int ks = 0; ks < 8; ks++) {
        const int k0 = (ks << 5) + (lkg << 3);
        bf16x8 a[3], bb[4];
#pragma unroll
        for (int m = 0; m < 3; m++)
            a[m] = *reinterpret_cast<const bf16x8*>(Ag + (size_t)((m << 4) + lrow) * 256 + k0);
#pragma unroll
        for (int n = 0; n < 4; n++)
            bb[n] = *reinterpret_cast<const bf16x8*>(Bg + (size_t)((n << 4) + lrow) * 256 + k0);
#pragma unroll
        for (int m = 0; m < 3; m++)
#pragma unroll
            for (int n = 0; n < 4; n++)
                qa[m][n] = __builtin_amdgcn_mfma_f32_16x16x32_bf16(a[m], bb[n], qa[m][n], 0, 0, 0);
    }
#pragma unroll
    for (int m = 0; m < 3; m++)
#pragma unroll
        for (int n = 0; n < 4; n++)
#pragma unroll
            for (int i = 0; i < 4; i++)
                smem[((m << 4) + (lkg << 2) + i) * 72 + (n << 4) + lrow] = f2b(qa[m][n][i] * 0.125f);
    __syncthreads();

    // ---- dots = Q(48x64) @ K^T (K stored [144][64]) ----
    const u16* Kg = Kb + (size_t)bh * 144 * 64;
    f32x4 da[3][9];
#pragma unroll
    for (int m = 0; m < 3; m++)
#pragma unroll
        for (int fc = 0; fc < 9; fc++)
#pragma unroll
            for (int i = 0; i < 4; i++) da[m][fc][i] = 0.f;
#pragma unroll
    for (int ks = 0; ks < 2; ks++) {
        const int k0 = (ks << 5) + (lkg << 3);
        bf16x8 aq[3];
#pragma unroll
        for (int m = 0; m < 3; m++)
            aq[m] = *reinterpret_cast<const bf16x8*>(smem + (size_t)((m << 4) + lrow) * 72 + k0);
#pragma unroll
        for (int fc = 0; fc < 9; fc++) {
            bf16x8 bk = *reinterpret_cast<const bf16x8*>(Kg + (size_t)((fc << 4) + lrow) * 64 + k0);
#pragma unroll
            for (int m = 0; m < 3; m++)
                da[m][fc] = __builtin_amdgcn_mfma_f32_16x16x32_bf16(aq[m], bk, da[m][fc], 0, 0, 0);
        }
    }
    __syncthreads();  // done reading Q region; P will overwrite

    // ---- softmax over 144 (row spread across 16 lanes x 9 frags) + write P bf16 ----
#pragma unroll
    for (int m = 0; m < 3; m++) {
#pragma unroll
        for (int i = 0; i < 4; i++) {
            float mx = -1e30f;
#pragma unroll
            for (int fc = 0; fc < 9; fc++) mx = fmaxf(mx, da[m][fc][i]);
#pragma unroll
            for (int s = 1; s < 16; s <<= 1) mx = fmaxf(mx, __shfl_xor(mx, s));
            float e[9];
            float sum = 0.f;
#pragma unroll
            for (int fc = 0; fc < 9; fc++) {
                e[fc] = __expf(da[m][fc][i] - mx);
                sum += e[fc];
            }
#pragma unroll
            for (int s = 1; s < 16; s <<= 1) sum += __shfl_xor(sum, s);
            float inv = 1.0f / sum;
            int r = (m << 4) + (lkg << 2) + i;
#pragma unroll
            for (int fc = 0; fc < 9; fc++) smem[r * 168 + (fc << 4) + lrow] = f2b(e[fc] * inv);
            smem[r * 168 + 144 + lrow] = 0;  // zero K-pad cols 144..159
        }
    }
    __syncthreads();

    // ---- out = P(48x160) @ V^T rows (Vt [64][160], zero-padded) ----
    const u16* Vg = Vt + (size_t)bh * 64 * 160;
    f32x4 oa[3][4];
#pragma unroll
    for (int m = 0; m < 3; m++)
#pragma unroll
        for (int n = 0; n < 4; n++)
#pragma unroll
            for (int i = 0; i < 4; i++) oa[m][n][i] = 0.f;
#pragma unroll
    for (int ks = 0; ks < 5; ks++) {
        const int k0 = (ks << 5) + (lkg << 3);
        bf16x8 pa[3];
#pragma unroll
        for (int m = 0; m < 3; m++)
            pa[m] = *reinterpret_cast<const bf16x8*>(smem + (size_t)((m << 4) + lrow) * 168 + k0);
#pragma unroll
        for (int n = 0; n < 4; n++) {
            bf16x8 bv = *reinterpret_cast<const bf16x8*>(Vg + (size_t)((n << 4) + lrow) * 160 + k0);
#pragma unroll
            for (int m = 0; m < 3; m++)
                oa[m][n] = __builtin_amdgcn_mfma_f32_16x16x32_bf16(pa[m], bv, oa[m][n], 0, 0, 0);
        }
    }

    // ---- scatter O to raster layout [b*7056+p][h*64+d] ----
#pragma unroll
    for (int m = 0; m < 3; m++)
#pragma unroll
        for (int n = 0; n < 4; n++)
#pragma unroll
            for (int i = 0; i < 4; i++) {
                int r = (m << 4) + (lkg << 2) + i;
                int q = t * 48 + r;          // row within batch, patch order
                int pi = q / 49, pos = q - pi * 49;
                int y = (pi / 12) * 7 + pos / 7;
                int xx = (pi - (pi / 12) * 12) * 7 + (pos - (pos / 7) * 7);
                O[(((size_t)b * 7056 + y * 84 + xx) << 9) + (h << 6) + (n << 4) + lrow] =
                    f2b(oa[m][n][i]);
            }
}

// ---------------- out-proj GEMM: [56448,512] @ [512,256] + bias -> fp32 out ----------------
__global__ __launch_bounds__(256) void k_outproj(const u16* __restrict__ A,
                                                 const u16* __restrict__ BT,
                                                 const float* __restrict__ bias,
                                                 float* __restrict__ out) {
    __shared__ u16 As[128][72];
    __shared__ u16 Bs[128][72];
    const int mt = blockIdx.x, nt = blockIdx.y;
    const int tid = threadIdx.x;
    const int wave = tid >> 6, lane = tid & 63;
    const int wr = wave >> 1, wc = wave & 1;
    const int lrow = lane & 15, lkg = lane >> 4;
    const u16* Ag = A + (size_t)(mt * 128) * 512;
    const u16* Bg = BT + (size_t)(nt * 128) * 512;
    const int srow = tid >> 3, scol = (tid & 7) << 3;
    f32x4 acc[4][4];
#pragma unroll
    for (int m = 0; m < 4; m++)
#pragma unroll
        for (int n = 0; n < 4; n++)
#pragma unroll
            for (int i = 0; i < 4; i++) acc[m][n][i] = 0.f;

    for (int ks = 0; ks < 8; ks++) {
        const int k0 = ks * 64;
        __syncthreads();
#pragma unroll
        for (int p = 0; p < 4; p++) {
            int rr = srow + (p << 5);
            *reinterpret_cast<bf16x8*>(&As[rr][scol]) =
                *reinterpret_cast<const bf16x8*>(Ag + (size_t)rr * 512 + k0 + scol);
            *reinterpret_cast<bf16x8*>(&Bs[rr][scol]) =
                *reinterpret_cast<const bf16x8*>(Bg + (size_t)rr * 512 + k0 + scol);
        }
        __syncthreads();
#pragma unroll
        for (int kk = 0; kk < 2; kk++) {
            const int ko = (kk << 5) + (lkg << 3);
            bf16x8 a[4], bb[4];
#pragma unroll
            for (int m = 0; m < 4; m++)
                a[m] = *reinterpret_cast<const bf16x8*>(&As[(wr << 6) + (m << 4) + lrow][ko]);
#pragma unroll
            for (int n = 0; n < 4; n++)
                bb[n] = *reinterpret_cast<const bf16x8*>(&Bs[(wc << 6) + (n << 4) + lrow][ko]);
#pragma unroll
            for (int m = 0; m < 4; m++)
#pragma unroll
                for (int n = 0; n < 4; n++)
                    acc[m][n] = __builtin_amdgcn_mfma_f32_16x16x32_bf16(a[m], bb[n], acc[m][n], 0, 0, 0);
        }
    }
#pragma unroll
    for (int m = 0; m < 4; m++)
#pragma unroll
        for (int n = 0; n < 4; n++)
#pragma unroll
            for (int i = 0; i < 4; i++) {
                int row = (mt << 7) + (wr << 6) + (m << 4) + (lkg << 2) + i;
                int col = (nt << 7) + (wc << 6) + (n << 4) + lrow;
                out[(size_t)row * 256 + col] = acc[m][n][i] + bias[col];
            }
}

extern "C" void kernel_launch(void* const* d_in, const int* in_sizes, int n_in,
                              void* d_out, int out_size, void* d_ws, size_t ws_size,
                              hipStream_t stream) {
    const float* x = (const float*)d_in[0];
    const float* w_q = (const float*)d_in[1];
    const float* w_kv = (const float*)d_in[2];
    const float* w_out = (const float*)d_in[3];
    const float* b_out = (const float*)d_in[4];
    float* out = (float*)d_out;

    char* ws = (char*)d_ws;
    size_t off = 0;
    auto alloc = [&](size_t bytes) -> char* {
        char* p = ws + off;
        off = (off + bytes + 255) & ~(size_t)255;
        return p;
    };
    u16* xp = (u16*)alloc(14450688ull * 2);     // x, patch order, bf16 [1152][12544]
    u16* wkvT = (u16*)alloc(12845056ull * 2);   // [1024][12544]
    u16* wqT = (u16*)alloc(131072ull * 2);      // [512][256]
    u16* woutT = (u16*)alloc(131072ull * 2);    // [256][512]
    u16* Kb = (u16*)alloc(1179648ull);          // [64][144][64] bf16
    u16* Vt = (u16*)alloc(1310720ull);          // [64][64][160] bf16 (zero-padded)
    u16* O = (u16*)alloc(57802752ull);          // [56448][512] bf16
    float* parts = (float*)alloc(33030144ull);  // [7][1152][1024] fp32

    hipMemsetAsync(Vt, 0, 1310720ull, stream);
    k_pack_x<<<7056, 256, 0, stream>>>(x, xp);
    k_tconv<<<dim3(32, 392), dim3(32, 8), 0, stream>>>(w_kv, wkvT, 12544, 1024);
    k_tconv<<<dim3(16, 8), dim3(32, 8), 0, stream>>>(w_q, wqT, 256, 512);
    k_tconv<<<dim3(8, 16), dim3(32, 8), 0, stream>>>(w_out, woutT, 512, 256);
    k_kvproj<<<dim3(9, 8, 7), 256, 0, stream>>>(xp, wkvT, parts);
    k_kvfin<<<4608, 256, 0, stream>>>(parts, Kb, Vt);
    k_attn<<<dim3(8, 147, 8), 64, 0, stream>>>(xp, wqT, Kb, Vt, O);
    k_outproj<<<dim3(441, 2), 256, 0, stream>>>(O, woutT, b_out, out);
}

// Round 3
// 294.897 us; speedup vs baseline: 1.0136x; 1.0136x over previous
//
#include <hip/hip_runtime.h>

typedef unsigned short u16;
typedef __bf16 bf16x8 __attribute__((ext_vector_type(8)));
typedef float f32x4 __attribute__((ext_vector_type(4)));

__device__ __forceinline__ u16 f2b(float f) {
    unsigned int u = __float_as_uint(f);
    u += 0x7fffu + ((u >> 16) & 1u);
    return (u16)(u >> 16);
}

// ---------------- pack x: NHWC fp32 -> patch-order bf16 ----------------
__global__ __launch_bounds__(256) void k_pack_x(const float* __restrict__ x,
                                                u16* __restrict__ xp) {
    int v = blockIdx.x * 256 + threadIdx.x;      // 1,806,336 total
    int c0 = (v & 31) << 3;                      // 8-channel chunk
    int pix = v >> 5;                            // 0..56447
    int b = pix / 7056;
    int r = pix - b * 7056;
    int y = r / 84;
    int xx = r - y * 84;
    int opix = (b * 144 + (y / 7) * 12 + (xx / 7)) * 49 + (y % 7) * 7 + (xx % 7);
    const float4* src = reinterpret_cast<const float4*>(x + ((size_t)pix << 8) + c0);
    float4 f0 = src[0], f1 = src[1];
    uint4 o;
    o.x = (unsigned)f2b(f0.x) | ((unsigned)f2b(f0.y) << 16);
    o.y = (unsigned)f2b(f0.z) | ((unsigned)f2b(f0.w) << 16);
    o.z = (unsigned)f2b(f1.x) | ((unsigned)f2b(f1.y) << 16);
    o.w = (unsigned)f2b(f1.z) | ((unsigned)f2b(f1.w) << 16);
    *reinterpret_cast<uint4*>(xp + ((size_t)opix << 8) + c0) = o;
}

// ---------------- transpose + convert: [R][C] fp32 -> [C][R] bf16 ----------------
__global__ __launch_bounds__(256) void k_tconv(const float* __restrict__ in,
                                               u16* __restrict__ out, int R, int C) {
    __shared__ float tile[32][33];
    int c0 = blockIdx.x << 5, r0 = blockIdx.y << 5;
    int tx = threadIdx.x, ty = threadIdx.y;  // 32 x 8
#pragma unroll
    for (int i = 0; i < 4; i++)
        tile[ty + (i << 3)][tx] = in[(size_t)(r0 + ty + (i << 3)) * C + c0 + tx];
    __syncthreads();
#pragma unroll
    for (int i = 0; i < 4; i++)
        out[(size_t)(c0 + ty + (i << 3)) * R + r0 + tx] = f2b(tile[tx][ty + (i << 3)]);
}

// ---------------- kv-proj GEMM: [1152,12544] @ [12544,1024], split-K=7 ----------------
__global__ __launch_bounds__(256) void k_kvproj(const u16* __restrict__ xp,
                                                const u16* __restrict__ wkvT,
                                                float* __restrict__ parts) {
    __shared__ u16 As[128][72];
    __shared__ u16 Bs[128][72];
    const int mt = blockIdx.x, nt = blockIdx.y, sp = blockIdx.z;
    const int tid = threadIdx.x;
    const int wave = tid >> 6, lane = tid & 63;
    const int wr = wave >> 1, wc = wave & 1;
    const int lrow = lane & 15, lkg = lane >> 4;
    const u16* Ag = xp + (size_t)(mt * 128) * 12544 + sp * 1792;
    const u16* Bg = wkvT + (size_t)(nt * 128) * 12544 + sp * 1792;
    const int srow = tid >> 3, scol = (tid & 7) << 3;
    f32x4 acc[4][4];
#pragma unroll
    for (int m = 0; m < 4; m++)
#pragma unroll
        for (int n = 0; n < 4; n++)
#pragma unroll
            for (int i = 0; i < 4; i++) acc[m][n][i] = 0.f;

    for (int ks = 0; ks < 28; ks++) {
        const int k0 = ks * 64;
        __syncthreads();
#pragma unroll
        for (int p = 0; p < 4; p++) {
            int rr = srow + (p << 5);
            *reinterpret_cast<bf16x8*>(&As[rr][scol]) =
                *reinterpret_cast<const bf16x8*>(Ag + (size_t)rr * 12544 + k0 + scol);
            *reinterpret_cast<bf16x8*>(&Bs[rr][scol]) =
                *reinterpret_cast<const bf16x8*>(Bg + (size_t)rr * 12544 + k0 + scol);
        }
        __syncthreads();
#pragma unroll
        for (int kk = 0; kk < 2; kk++) {
            const int ko = (kk << 5) + (lkg << 3);
            bf16x8 a[4], bb[4];
#pragma unroll
            for (int m = 0; m < 4; m++)
                a[m] = *reinterpret_cast<const bf16x8*>(&As[(wr << 6) + (m << 4) + lrow][ko]);
#pragma unroll
            for (int n = 0; n < 4; n++)
                bb[n] = *reinterpret_cast<const bf16x8*>(&Bs[(wc << 6) + (n << 4) + lrow][ko]);
#pragma unroll
            for (int m = 0; m < 4; m++)
#pragma unroll
                for (int n = 0; n < 4; n++)
                    acc[m][n] = __builtin_amdgcn_mfma_f32_16x16x32_bf16(a[m], bb[n], acc[m][n], 0, 0, 0);
        }
    }
    float* outp = parts + (size_t)sp * 1179648;
#pragma unroll
    for (int m = 0; m < 4; m++)
#pragma unroll
        for (int n = 0; n < 4; n++)
#pragma unroll
            for (int i = 0; i < 4; i++) {
                int row = (mt << 7) + (wr << 6) + (m << 4) + (lkg << 2) + i;
                int col = (nt << 7) + (wc << 6) + (n << 4) + lrow;
                outp[(size_t)row * 1024 + col] = acc[m][n][i];
            }
}

// ---------------- reduce split-K partials -> K bf16 [bh][144][64], V^T bf16 [bh][64][160] ----------------
__global__ __launch_bounds__(256) void k_kvfin(const float* __restrict__ parts,
                                               u16* __restrict__ Kb, u16* __restrict__ Vt) {
    int idx = blockIdx.x * 256 + threadIdx.x;  // < 1152*1024
    int m = idx >> 10, n = idx & 1023;
    float s = 0.f;
#pragma unroll
    for (int sp = 0; sp < 7; sp++) s += parts[(size_t)sp * 1179648 + idx];
    int b = m / 144, pi = m - b * 144;
    int h = (n & 511) >> 6, d = n & 63;
    int bh = (b << 3) + h;
    if (n < 512)
        Kb[((size_t)bh * 144 + pi) * 64 + d] = f2b(s);
    else
        Vt[((size_t)bh * 64 + d) * 160 + pi] = f2b(s);
}

// ---------------- fused q-proj + attention (1 wave / block) ----------------
// LDS 9984B, uniform stride 104 (conflict-free for 16-row b128 reads).
// Stage order identical to round-1 (proven): Q | dots(all m) | softmax+P-A | PV-A | P-B | PV-B.
__global__ __launch_bounds__(64, 4) void k_attn(const u16* __restrict__ xp,
                                                const u16* __restrict__ wqT,
                                                const u16* __restrict__ Kb,
                                                const u16* __restrict__ Vt,
                                                u16* __restrict__ O) {
    __shared__ u16 smem[48 * 104];
    const int h = blockIdx.x, t = blockIdx.y, b = blockIdx.z;
    const int lane = threadIdx.x;
    const int lrow = lane & 15, lkg = lane >> 4;
    const int bh = (b << 3) + h;

    // ---- Stage 1: Q = Xtile(48x256) @ WqT(64x256)^T, scaled by 0.125 ----
    const u16* Ag = xp + ((size_t)b * 7056 + (size_t)t * 48) * 256;
    const u16* Bg = wqT + ((size_t)h * 64) * 256;
    f32x4 qa[3][4];
#pragma unroll
    for (int m = 0; m < 3; m++)
#pragma unroll
        for (int n = 0; n < 4; n++)
#pragma unroll
            for (int i = 0; i < 4; i++) qa[m][n][i] = 0.f;
#pragma unroll
    for (int ks = 0; ks < 8; ks++) {
        const int k0 = (ks << 5) + (lkg << 3);
        bf16x8 a[3], bb[4];
#pragma unroll
        for (int m = 0; m < 3; m++)
            a[m] = *reinterpret_cast<const bf16x8*>(Ag + (size_t)((m << 4) + lrow) * 256 + k0);
#pragma unroll
        for (int n = 0; n < 4; n++)
            bb[n] = *reinterpret_cast<const bf16x8*>(Bg + (size_t)((n << 4) + lrow) * 256 + k0);
#pragma unroll
        for (int m = 0; m < 3; m++)
#pragma unroll
            for (int n = 0; n < 4; n++)
                qa[m][n] = __builtin_amdgcn_mfma_f32_16x16x32_bf16(a[m], bb[n], qa[m][n], 0, 0, 0);
    }
#pragma unroll
    for (int m = 0; m < 3; m++)
#pragma unroll
        for (int n = 0; n < 4; n++)
#pragma unroll
            for (int i = 0; i < 4; i++)
                smem[((m << 4) + (lkg << 2) + i) * 104 + (n << 4) + lrow] = f2b(qa[m][n][i] * 0.125f);
    __syncthreads();

    // ---- Stage 2: dots = Q(48x64) @ K^T for ALL m-blocks (Q still live) ----
    const u16* Kg = Kb + (size_t)bh * 9216;
    f32x4 da[3][9];
#pragma unroll
    for (int m = 0; m < 3; m++)
#pragma unroll
        for (int fc = 0; fc < 9; fc++)
#pragma unroll
            for (int i = 0; i < 4; i++) da[m][fc][i] = 0.f;
#pragma unroll
    for (int ks = 0; ks < 2; ks++) {
        const int k0 = (ks << 5) + (lkg << 3);
        bf16x8 aq[3];
#pragma unroll
        for (int m = 0; m < 3; m++)
            aq[m] = *reinterpret_cast<const bf16x8*>(smem + (size_t)((m << 4) + lrow) * 104 + k0);
#pragma unroll
        for (int fc = 0; fc < 9; fc++) {
            bf16x8 bk = *reinterpret_cast<const bf16x8*>(Kg + (size_t)((fc << 4) + lrow) * 64 + k0);
#pragma unroll
            for (int m = 0; m < 3; m++)
                da[m][fc] = __builtin_amdgcn_mfma_f32_16x16x32_bf16(aq[m], bk, da[m][fc], 0, 0, 0);
        }
    }
    __syncthreads();  // Q dead; P chunk A will overwrite

    // ---- Stage 3: softmax; write P keys 0..79 (+ zero slots 80..95); pack keys 80..143 ----
    unsigned pk[3][4][2];
#pragma unroll
    for (int m = 0; m < 3; m++) {
#pragma unroll
        for (int i = 0; i < 4; i++) {
            float mx = -1e30f;
#pragma unroll
            for (int fc = 0; fc < 9; fc++) mx = fmaxf(mx, da[m][fc][i]);
#pragma unroll
            for (int s = 1; s < 16; s <<= 1) mx = fmaxf(mx, __shfl_xor(mx, s));
            float e[9];
            float sum = 0.f;
#pragma unroll
            for (int fc = 0; fc < 9; fc++) {
                e[fc] = __expf(da[m][fc][i] - mx);
                sum += e[fc];
            }
#pragma unroll
            for (int s = 1; s < 16; s <<= 1) sum += __shfl_xor(sum, s);
            float inv = 1.0f / sum;
            int r = (m << 4) + (lkg << 2) + i;
#pragma unroll
            for (int fc = 0; fc < 5; fc++) smem[r * 104 + (fc << 4) + lrow] = f2b(e[fc] * inv);
            smem[r * 104 + 80 + lrow] = 0;  // zero slots 80..95
            pk[m][i][0] = (unsigned)f2b(e[5] * inv) | ((unsigned)f2b(e[6] * inv) << 16);
            pk[m][i][1] = (unsigned)f2b(e[7] * inv) | ((unsigned)f2b(e[8] * inv) << 16);
        }
    }
    __syncthreads();

    // ---- Stage 4: PV chunk A — key slots 0..95 (80 real + 16 zero) ----
    const u16* Vg = Vt + (size_t)bh * 10240;
    f32x4 oa[3][4];
#pragma unroll
    for (int m = 0; m < 3; m++)
#pragma unroll
        for (int n = 0; n < 4; n++)
#pragma unroll
            for (int i = 0; i < 4; i++) oa[m][n][i] = 0.f;
#pragma unroll
    for (int ks = 0; ks < 3; ks++) {
        const int k0 = (ks << 5) + (lkg << 3);
        bf16x8 pa[3];
#pragma unroll
        for (int m = 0; m < 3; m++)
            pa[m] = *reinterpret_cast<const bf16x8*>(smem + (size_t)((m << 4) + lrow) * 104 + k0);
#pragma unroll
        for (int n = 0; n < 4; n++) {
            bf16x8 bv = *reinterpret_cast<const bf16x8*>(Vg + (size_t)((n << 4) + lrow) * 160 + k0);
#pragma unroll
            for (int m = 0; m < 3; m++)
                oa[m][n] = __builtin_amdgcn_mfma_f32_16x16x32_bf16(pa[m], bv, oa[m][n], 0, 0, 0);
        }
    }
    __syncthreads();  // P-A reads done; P-B overwrites same region

    // ---- Stage 5: store P keys 80..143 -> slots 0..63 ----
#pragma unroll
    for (int m = 0; m < 3; m++)
#pragma unroll
        for (int i = 0; i < 4; i++) {
            int r = (m << 4) + (lkg << 2) + i;
            smem[r * 104 + lrow]      = (u16)(pk[m][i][0] & 0xffffu);
            smem[r * 104 + 16 + lrow] = (u16)(pk[m][i][0] >> 16);
            smem[r * 104 + 32 + lrow] = (u16)(pk[m][i][1] & 0xffffu);
            smem[r * 104 + 48 + lrow] = (u16)(pk[m][i][1] >> 16);
        }
    __syncthreads();

    // ---- Stage 6: PV chunk B — keys 80..143 ----
#pragma unroll
    for (int ks = 0; ks < 2; ks++) {
        const int k0 = (ks << 5) + (lkg << 3);
        bf16x8 pa[3];
#pragma unroll
        for (int m = 0; m < 3; m++)
            pa[m] = *reinterpret_cast<const bf16x8*>(smem + (size_t)((m << 4) + lrow) * 104 + k0);
#pragma unroll
        for (int n = 0; n < 4; n++) {
            bf16x8 bv = *reinterpret_cast<const bf16x8*>(Vg + (size_t)((n << 4) + lrow) * 160 + 80 + k0);
#pragma unroll
            for (int m = 0; m < 3; m++)
                oa[m][n] = __builtin_amdgcn_mfma_f32_16x16x32_bf16(pa[m], bv, oa[m][n], 0, 0, 0);
        }
    }

    // ---- scatter O to raster layout [b*7056+p][h*64+d] ----
#pragma unroll
    for (int m = 0; m < 3; m++)
#pragma unroll
        for (int n = 0; n < 4; n++)
#pragma unroll
            for (int i = 0; i < 4; i++) {
                int r = (m << 4) + (lkg << 2) + i;
                int q = t * 48 + r;          // row within batch, patch order
                int pi = q / 49, pos = q - pi * 49;
                int y = (pi / 12) * 7 + pos / 7;
                int xx = (pi - (pi / 12) * 12) * 7 + (pos - (pos / 7) * 7);
                O[(((size_t)b * 7056 + y * 84 + xx) << 9) + (h << 6) + (n << 4) + lrow] =
                    f2b(oa[m][n][i]);
            }
}

// ---------------- out-proj GEMM: [56448,512] @ [512,256] + bias -> fp32 out ----------------
__global__ __launch_bounds__(256) void k_outproj(const u16* __restrict__ A,
                                                 const u16* __restrict__ BT,
                                                 const float* __restrict__ bias,
                                                 float* __restrict__ out) {
    __shared__ u16 As[128][72];
    __shared__ u16 Bs[128][72];
    const int mt = blockIdx.x, nt = blockIdx.y;
    const int tid = threadIdx.x;
    const int wave = tid >> 6, lane = tid & 63;
    const int wr = wave >> 1, wc = wave & 1;
    const int lrow = lane & 15, lkg = lane >> 4;
    const u16* Ag = A + (size_t)(mt * 128) * 512;
    const u16* Bg = BT + (size_t)(nt * 128) * 512;
    const int srow = tid >> 3, scol = (tid & 7) << 3;
    f32x4 acc[4][4];
#pragma unroll
    for (int m = 0; m < 4; m++)
#pragma unroll
        for (int n = 0; n < 4; n++)
#pragma unroll
            for (int i = 0; i < 4; i++) acc[m][n][i] = 0.f;

    for (int ks = 0; ks < 8; ks++) {
        const int k0 = ks * 64;
        __syncthreads();
#pragma unroll
        for (int p = 0; p < 4; p++) {
            int rr = srow + (p << 5);
            *reinterpret_cast<bf16x8*>(&As[rr][scol]) =
                *reinterpret_cast<const bf16x8*>(Ag + (size_t)rr * 512 + k0 + scol);
            *reinterpret_cast<bf16x8*>(&Bs[rr][scol]) =
                *reinterpret_cast<const bf16x8*>(Bg + (size_t)rr * 512 + k0 + scol);
        }
        __syncthreads();
#pragma unroll
        for (int kk = 0; kk < 2; kk++) {
            const int ko = (kk << 5) + (lkg << 3);
            bf16x8 a[4], bb[4];
#pragma unroll
            for (int m = 0; m < 4; m++)
                a[m] = *reinterpret_cast<const bf16x8*>(&As[(wr << 6) + (m << 4) + lrow][ko]);
#pragma unroll
            for (int n = 0; n < 4; n++)
                bb[n] = *reinterpret_cast<const bf16x8*>(&Bs[(wc << 6) + (n << 4) + lrow][ko]);
#pragma unroll
            for (int m = 0; m < 4; m++)
#pragma unroll
                for (int n = 0; n < 4; n++)
                    acc[m][n] = __builtin_amdgcn_mfma_f32_16x16x32_bf16(a[m], bb[n], acc[m][n], 0, 0, 0);
        }
    }
#pragma unroll
    for (int m = 0; m < 4; m++)
#pragma unroll
        for (int n = 0; n < 4; n++)
#pragma unroll
            for (int i = 0; i < 4; i++) {
                int row = (mt << 7) + (wr << 6) + (m << 4) + (lkg << 2) + i;
                int col = (nt << 7) + (wc << 6) + (n << 4) + lrow;
                out[(size_t)row * 256 + col] = acc[m][n][i] + bias[col];
            }
}

extern "C" void kernel_launch(void* const* d_in, const int* in_sizes, int n_in,
                              void* d_out, int out_size, void* d_ws, size_t ws_size,
                              hipStream_t stream) {
    const float* x = (const float*)d_in[0];
    const float* w_q = (const float*)d_in[1];
    const float* w_kv = (const float*)d_in[2];
    const float* w_out = (const float*)d_in[3];
    const float* b_out = (const float*)d_in[4];
    float* out = (float*)d_out;

    char* ws = (char*)d_ws;
    size_t off = 0;
    auto alloc = [&](size_t bytes) -> char* {
        char* p = ws + off;
        off = (off + bytes + 255) & ~(size_t)255;
        return p;
    };
    u16* xp = (u16*)alloc(14450688ull * 2);     // x, patch order, bf16 [1152][12544]
    u16* wkvT = (u16*)alloc(12845056ull * 2);   // [1024][12544]
    u16* wqT = (u16*)alloc(131072ull * 2);      // [512][256]
    u16* woutT = (u16*)alloc(131072ull * 2);    // [256][512]
    u16* Kb = (u16*)alloc(1179648ull);          // [64][144][64] bf16
    u16* Vt = (u16*)alloc(1310720ull);          // [64][64][160] bf16 (pad cols never read)
    u16* O = (u16*)alloc(57802752ull);          // [56448][512] bf16
    float* parts = (float*)alloc(33030144ull);  // [7][1152][1024] fp32

    k_pack_x<<<7056, 256, 0, stream>>>(x, xp);
    k_tconv<<<dim3(32, 392), dim3(32, 8), 0, stream>>>(w_kv, wkvT, 12544, 1024);
    k_tconv<<<dim3(16, 8), dim3(32, 8), 0, stream>>>(w_q, wqT, 256, 512);
    k_tconv<<<dim3(8, 16), dim3(32, 8), 0, stream>>>(w_out, woutT, 512, 256);
    k_kvproj<<<dim3(9, 8, 7), 256, 0, stream>>>(xp, wkvT, parts);
    k_kvfin<<<4608, 256, 0, stream>>>(parts, Kb, Vt);
    k_attn<<<dim3(8, 147, 8), 64, 0, stream>>>(xp, wqT, Kb, Vt, O);
    k_outproj<<<dim3(441, 2), 256, 0, stream>>>(O, woutT, b_out, out);
}

// Round 5
// 293.650 us; speedup vs baseline: 1.0179x; 1.0042x over previous
//
#include <hip/hip_runtime.h>

typedef unsigned short u16;
typedef __bf16 bf16x8 __attribute__((ext_vector_type(8)));
typedef float f32x4 __attribute__((ext_vector_type(4)));

__device__ __forceinline__ u16 f2b(float f) {
    unsigned int u = __float_as_uint(f);
    u += 0x7fffu + ((u >> 16) & 1u);
    return (u16)(u >> 16);
}

// ---------------- pack x: NHWC fp32 -> patch-order bf16 ----------------
__global__ __launch_bounds__(256) void k_pack_x(const float* __restrict__ x,
                                                u16* __restrict__ xp) {
    int v = blockIdx.x * 256 + threadIdx.x;      // 1,806,336 total
    int c0 = (v & 31) << 3;                      // 8-channel chunk
    int pix = v >> 5;                            // 0..56447
    int b = pix / 7056;
    int r = pix - b * 7056;
    int y = r / 84;
    int xx = r - y * 84;
    int opix = (b * 144 + (y / 7) * 12 + (xx / 7)) * 49 + (y % 7) * 7 + (xx % 7);
    const float4* src = reinterpret_cast<const float4*>(x + ((size_t)pix << 8) + c0);
    float4 f0 = src[0], f1 = src[1];
    uint4 o;
    o.x = (unsigned)f2b(f0.x) | ((unsigned)f2b(f0.y) << 16);
    o.y = (unsigned)f2b(f0.z) | ((unsigned)f2b(f0.w) << 16);
    o.z = (unsigned)f2b(f1.x) | ((unsigned)f2b(f1.y) << 16);
    o.w = (unsigned)f2b(f1.z) | ((unsigned)f2b(f1.w) << 16);
    *reinterpret_cast<uint4*>(xp + ((size_t)opix << 8) + c0) = o;
}

// ---------------- transpose + convert + scale: [R][C] fp32 -> [C][R] bf16 ----------------
__global__ __launch_bounds__(256) void k_tconv(const float* __restrict__ in,
                                               u16* __restrict__ out, int R, int C,
                                               float scale) {
    __shared__ float tile[32][33];
    int c0 = blockIdx.x << 5, r0 = blockIdx.y << 5;
    int tx = threadIdx.x, ty = threadIdx.y;  // 32 x 8
#pragma unroll
    for (int i = 0; i < 4; i++)
        tile[ty + (i << 3)][tx] = in[(size_t)(r0 + ty + (i << 3)) * C + c0 + tx];
    __syncthreads();
#pragma unroll
    for (int i = 0; i < 4; i++)
        out[(size_t)(c0 + ty + (i << 3)) * R + r0 + tx] = f2b(tile[tx][ty + (i << 3)] * scale);
}

// ---------------- kv-proj GEMM: [1152,12544] @ [12544,1024], split-K=7 ----------------
__global__ __launch_bounds__(256) void k_kvproj(const u16* __restrict__ xp,
                                                const u16* __restrict__ wkvT,
                                                float* __restrict__ parts) {
    __shared__ u16 As[128][72];
    __shared__ u16 Bs[128][72];
    const int mt = blockIdx.x, nt = blockIdx.y, sp = blockIdx.z;
    const int tid = threadIdx.x;
    const int wave = tid >> 6, lane = tid & 63;
    const int wr = wave >> 1, wc = wave & 1;
    const int lrow = lane & 15, lkg = lane >> 4;
    const u16* Ag = xp + (size_t)(mt * 128) * 12544 + sp * 1792;
    const u16* Bg = wkvT + (size_t)(nt * 128) * 12544 + sp * 1792;
    const int srow = tid >> 3, scol = (tid & 7) << 3;
    f32x4 acc[4][4];
#pragma unroll
    for (int m = 0; m < 4; m++)
#pragma unroll
        for (int n = 0; n < 4; n++)
#pragma unroll
            for (int i = 0; i < 4; i++) acc[m][n][i] = 0.f;

    for (int ks = 0; ks < 28; ks++) {
        const int k0 = ks * 64;
        __syncthreads();
#pragma unroll
        for (int p = 0; p < 4; p++) {
            int rr = srow + (p << 5);
            *reinterpret_cast<bf16x8*>(&As[rr][scol]) =
                *reinterpret_cast<const bf16x8*>(Ag + (size_t)rr * 12544 + k0 + scol);
            *reinterpret_cast<bf16x8*>(&Bs[rr][scol]) =
                *reinterpret_cast<const bf16x8*>(Bg + (size_t)rr * 12544 + k0 + scol);
        }
        __syncthreads();
#pragma unroll
        for (int kk = 0; kk < 2; kk++) {
            const int ko = (kk << 5) + (lkg << 3);
            bf16x8 a[4], bb[4];
#pragma unroll
            for (int m = 0; m < 4; m++)
                a[m] = *reinterpret_cast<const bf16x8*>(&As[(wr << 6) + (m << 4) + lrow][ko]);
#pragma unroll
            for (int n = 0; n < 4; n++)
                bb[n] = *reinterpret_cast<const bf16x8*>(&Bs[(wc << 6) + (n << 4) + lrow][ko]);
#pragma unroll
            for (int m = 0; m < 4; m++)
#pragma unroll
                for (int n = 0; n < 4; n++)
                    acc[m][n] = __builtin_amdgcn_mfma_f32_16x16x32_bf16(a[m], bb[n], acc[m][n], 0, 0, 0);
        }
    }
    float* outp = parts + (size_t)sp * 1179648;
#pragma unroll
    for (int m = 0; m < 4; m++)
#pragma unroll
        for (int n = 0; n < 4; n++)
#pragma unroll
            for (int i = 0; i < 4; i++) {
                int row = (mt << 7) + (wr << 6) + (m << 4) + (lkg << 2) + i;
                int col = (nt << 7) + (wc << 6) + (n << 4) + lrow;
                outp[(size_t)row * 1024 + col] = acc[m][n][i];
            }
}

// ---------------- reduce split-K partials -> K bf16 [bh][144][64], V^T bf16 [bh][64][160] ----------------
__global__ __launch_bounds__(256) void k_kvfin(const float* __restrict__ parts,
                                               u16* __restrict__ Kb, u16* __restrict__ Vt) {
    int idx = blockIdx.x * 256 + threadIdx.x;  // < 1152*1024
    int m = idx >> 10, n = idx & 1023;
    float s = 0.f;
#pragma unroll
    for (int sp = 0; sp < 7; sp++) s += parts[(size_t)sp * 1179648 + idx];
    int b = m / 144, pi = m - b * 144;
    int h = (n & 511) >> 6, d = n & 63;
    int bh = (b << 3) + h;
    if (n < 512)
        Kb[((size_t)bh * 144 + pi) * 64 + d] = f2b(s);
    else
        Vt[((size_t)bh * 64 + d) * 160 + pi] = f2b(s);
}

// ---------------- q-proj GEMM: [56448,256] @ [256,512] -> Qb [bh][7056][64] bf16 ----------------
// wqT is pre-scaled by 0.125. Grid (441, 4): nt covers the 512 output columns.
__global__ __launch_bounds__(256) void k_qproj(const u16* __restrict__ xp,
                                               const u16* __restrict__ wqT,
                                               u16* __restrict__ Qb) {
    __shared__ u16 As[128][72];
    __shared__ u16 Bs[128][72];
    const int mt = blockIdx.x, nt = blockIdx.y;  // 441 x 4
    const int tid = threadIdx.x;
    const int wave = tid >> 6, lane = tid & 63;
    const int wr = wave >> 1, wc = wave & 1;
    const int lrow = lane & 15, lkg = lane >> 4;
    const u16* Ag = xp + (size_t)(mt * 128) * 256;
    const u16* Bg = wqT + (size_t)(nt * 128) * 256;
    const int srow = tid >> 3, scol = (tid & 7) << 3;
    f32x4 acc[4][4];
#pragma unroll
    for (int m = 0; m < 4; m++)
#pragma unroll
        for (int n = 0; n < 4; n++)
#pragma unroll
            for (int i = 0; i < 4; i++) acc[m][n][i] = 0.f;

    for (int ks = 0; ks < 4; ks++) {
        const int k0 = ks * 64;
        __syncthreads();
#pragma unroll
        for (int p = 0; p < 4; p++) {
            int rr = srow + (p << 5);
            *reinterpret_cast<bf16x8*>(&As[rr][scol]) =
                *reinterpret_cast<const bf16x8*>(Ag + (size_t)rr * 256 + k0 + scol);
            *reinterpret_cast<bf16x8*>(&Bs[rr][scol]) =
                *reinterpret_cast<const bf16x8*>(Bg + (size_t)rr * 256 + k0 + scol);
        }
        __syncthreads();
#pragma unroll
        for (int kk = 0; kk < 2; kk++) {
            const int ko = (kk << 5) + (lkg << 3);
            bf16x8 a[4], bb[4];
#pragma unroll
            for (int m = 0; m < 4; m++)
                a[m] = *reinterpret_cast<const bf16x8*>(&As[(wr << 6) + (m << 4) + lrow][ko]);
#pragma unroll
            for (int n = 0; n < 4; n++)
                bb[n] = *reinterpret_cast<const bf16x8*>(&Bs[(wc << 6) + (n << 4) + lrow][ko]);
#pragma unroll
            for (int m = 0; m < 4; m++)
#pragma unroll
                for (int n = 0; n < 4; n++)
                    acc[m][n] = __builtin_amdgcn_mfma_f32_16x16x32_bf16(a[m], bb[n], acc[m][n], 0, 0, 0);
        }
    }
    // write Q[row in patch order][col=h*64+d] -> Qb[(b*8+h)*451584 + pp*64 + d]
#pragma unroll
    for (int m = 0; m < 4; m++)
#pragma unroll
        for (int n = 0; n < 4; n++)
#pragma unroll
            for (int i = 0; i < 4; i++) {
                int row = (mt << 7) + (wr << 6) + (m << 4) + (lkg << 2) + i;
                int col = (nt << 7) + (wc << 6) + (n << 4) + lrow;  // 0..511
                int b = row / 7056, pp = row - b * 7056;
                int h = col >> 6, d = col & 63;
                Qb[(size_t)((b << 3) + h) * 451584 + (size_t)pp * 64 + d] = f2b(acc[m][n][i]);
            }
}

// ---------------- attention (1 wave / block, 16 q-rows) ----------------
// LDS 3328B = P tile [16][104] (two key-chunks through one buffer).
__global__ __launch_bounds__(64, 4) void k_attn(const u16* __restrict__ Qb,
                                                const u16* __restrict__ Kb,
                                                const u16* __restrict__ Vt,
                                                u16* __restrict__ O) {
    __shared__ u16 smem[16 * 104];
    const int t = blockIdx.x, h = blockIdx.y, b = blockIdx.z;
    const int lane = threadIdx.x;
    const int lrow = lane & 15, lkg = lane >> 4;
    const int bh = (b << 3) + h;

    // ---- dots = Q(16x64) @ K^T ----
    const u16* Qg = Qb + (size_t)bh * 451584 + (size_t)(t << 4) * 64;
    const u16* Kg = Kb + (size_t)bh * 9216;
    f32x4 da[9];
#pragma unroll
    for (int fc = 0; fc < 9; fc++)
#pragma unroll
        for (int i = 0; i < 4; i++) da[fc][i] = 0.f;
#pragma unroll
    for (int ks = 0; ks < 2; ks++) {
        const int k0 = (ks << 5) + (lkg << 3);
        bf16x8 aq = *reinterpret_cast<const bf16x8*>(Qg + (size_t)lrow * 64 + k0);
#pragma unroll
        for (int fc = 0; fc < 9; fc++) {
            bf16x8 bk = *reinterpret_cast<const bf16x8*>(Kg + (size_t)((fc << 4) + lrow) * 64 + k0);
            da[fc] = __builtin_amdgcn_mfma_f32_16x16x32_bf16(aq, bk, da[fc], 0, 0, 0);
        }
    }

    // ---- softmax; write P keys 0..79 (+ zero slots 80..95); pack keys 80..143 ----
    unsigned pk[4][2];
#pragma unroll
    for (int i = 0; i < 4; i++) {
        float mx = -1e30f;
#pragma unroll
        for (int fc = 0; fc < 9; fc++) mx = fmaxf(mx, da[fc][i]);
#pragma unroll
        for (int s = 1; s < 16; s <<= 1) mx = fmaxf(mx, __shfl_xor(mx, s));
        float e[9];
        float sum = 0.f;
#pragma unroll
        for (int fc = 0; fc < 9; fc++) {
            e[fc] = __expf(da[fc][i] - mx);
            sum += e[fc];
        }
#pragma unroll
        for (int s = 1; s < 16; s <<= 1) sum += __shfl_xor(sum, s);
        float inv = 1.0f / sum;
        int r = (lkg << 2) + i;
#pragma unroll
        for (int fc = 0; fc < 5; fc++) smem[r * 104 + (fc << 4) + lrow] = f2b(e[fc] * inv);
        smem[r * 104 + 80 + lrow] = 0;  // zero slots 80..95
        pk[i][0] = (unsigned)f2b(e[5] * inv) | ((unsigned)f2b(e[6] * inv) << 16);
        pk[i][1] = (unsigned)f2b(e[7] * inv) | ((unsigned)f2b(e[8] * inv) << 16);
    }
    __syncthreads();

    // ---- PV chunk A: key slots 0..95 (80 real + 16 zero) ----
    const u16* Vg = Vt + (size_t)bh * 10240;
    f32x4 oa[4];
#pragma unroll
    for (int n = 0; n < 4; n++)
#pragma unroll
        for (int i = 0; i < 4; i++) oa[n][i] = 0.f;
#pragma unroll
    for (int ks = 0; ks < 3; ks++) {
        const int k0 = (ks << 5) + (lkg << 3);
        bf16x8 pa = *reinterpret_cast<const bf16x8*>(smem + (size_t)lrow * 104 + k0);
#pragma unroll
        for (int n = 0; n < 4; n++) {
            bf16x8 bv = *reinterpret_cast<const bf16x8*>(Vg + (size_t)((n << 4) + lrow) * 160 + k0);
            oa[n] = __builtin_amdgcn_mfma_f32_16x16x32_bf16(pa, bv, oa[n], 0, 0, 0);
        }
    }
    __syncthreads();  // P-A reads done; P-B overwrites same region

    // ---- store P keys 80..143 -> slots 0..63 ----
#pragma unroll
    for (int i = 0; i < 4; i++) {
        int r = (lkg << 2) + i;
        smem[r * 104 + lrow]      = (u16)(pk[i][0] & 0xffffu);
        smem[r * 104 + 16 + lrow] = (u16)(pk[i][0] >> 16);
        smem[r * 104 + 32 + lrow] = (u16)(pk[i][1] & 0xffffu);
        smem[r * 104 + 48 + lrow] = (u16)(pk[i][1] >> 16);
    }
    __syncthreads();

    // ---- PV chunk B: keys 80..143 ----
#pragma unroll
    for (int ks = 0; ks < 2; ks++) {
        const int k0 = (ks << 5) + (lkg << 3);
        bf16x8 pa = *reinterpret_cast<const bf16x8*>(smem + (size_t)lrow * 104 + k0);
#pragma unroll
        for (int n = 0; n < 4; n++) {
            bf16x8 bv = *reinterpret_cast<const bf16x8*>(Vg + (size_t)((n << 4) + lrow) * 160 + 80 + k0);
            oa[n] = __builtin_amdgcn_mfma_f32_16x16x32_bf16(pa, bv, oa[n], 0, 0, 0);
        }
    }

    // ---- scatter O to raster layout [b*7056+p][h*64+d] ----
#pragma unroll
    for (int n = 0; n < 4; n++)
#pragma unroll
        for (int i = 0; i < 4; i++) {
            int r = (lkg << 2) + i;
            int q = (t << 4) + r;        // row within batch, patch order
            int pi = q / 49, pos = q - pi * 49;
            int y = (pi / 12) * 7 + pos / 7;
            int xx = (pi - (pi / 12) * 12) * 7 + (pos - (pos / 7) * 7);
            O[(((size_t)b * 7056 + y * 84 + xx) << 9) + (h << 6) + (n << 4) + lrow] =
                f2b(oa[n][i]);
        }
}

// ---------------- out-proj GEMM: [56448,512] @ [512,256] + bias -> fp32 out ----------------
__global__ __launch_bounds__(256) void k_outproj(const u16* __restrict__ A,
                                                 const u16* __restrict__ BT,
                                                 const float* __restrict__ bias,
                                                 float* __restrict__ out) {
    __shared__ u16 As[128][72];
    __shared__ u16 Bs[128][72];
    const int mt = blockIdx.x, nt = blockIdx.y;
    const int tid = threadIdx.x;
    const int wave = tid >> 6, lane = tid & 63;
    const int wr = wave >> 1, wc = wave & 1;
    const int lrow = lane & 15, lkg = lane >> 4;
    const u16* Ag = A + (size_t)(mt * 128) * 512;
    const u16* Bg = BT + (size_t)(nt * 128) * 512;
    const int srow = tid >> 3, scol = (tid & 7) << 3;
    f32x4 acc[4][4];
#pragma unroll
    for (int m = 0; m < 4; m++)
#pragma unroll
        for (int n = 0; n < 4; n++)
#pragma unroll
            for (int i = 0; i < 4; i++) acc[m][n][i] = 0.f;

    for (int ks = 0; ks < 8; ks++) {
        const int k0 = ks * 64;
        __syncthreads();
#pragma unroll
        for (int p = 0; p < 4; p++) {
            int rr = srow + (p << 5);
            *reinterpret_cast<bf16x8*>(&As[rr][scol]) =
                *reinterpret_cast<const bf16x8*>(Ag + (size_t)rr * 512 + k0 + scol);
            *reinterpret_cast<bf16x8*>(&Bs[rr][scol]) =
                *reinterpret_cast<const bf16x8*>(Bg + (size_t)rr * 512 + k0 + scol);
        }
        __syncthreads();
#pragma unroll
        for (int kk = 0; kk < 2; kk++) {
            const int ko = (kk << 5) + (lkg << 3);
            bf16x8 a[4], bb[4];
#pragma unroll
            for (int m = 0; m < 4; m++)
                a[m] = *reinterpret_cast<const bf16x8*>(&As[(wr << 6) + (m << 4) + lrow][ko]);
#pragma unroll
            for (int n = 0; n < 4; n++)
                bb[n] = *reinterpret_cast<const bf16x8*>(&Bs[(wc << 6) + (n << 4) + lrow][ko]);
#pragma unroll
            for (int m = 0; m < 4; m++)
#pragma unroll
                for (int n = 0; n < 4; n++)
                    acc[m][n] = __builtin_amdgcn_mfma_f32_16x16x32_bf16(a[m], bb[n], acc[m][n], 0, 0, 0);
        }
    }
#pragma unroll
    for (int m = 0; m < 4; m++)
#pragma unroll
        for (int n = 0; n < 4; n++)
#pragma unroll
            for (int i = 0; i < 4; i++) {
                int row = (mt << 7) + (wr << 6) + (m << 4) + (lkg << 2) + i;
                int col = (nt << 7) + (wc << 6) + (n << 4) + lrow;
                out[(size_t)row * 256 + col] = acc[m][n][i] + bias[col];
            }
}

extern "C" void kernel_launch(void* const* d_in, const int* in_sizes, int n_in,
                              void* d_out, int out_size, void* d_ws, size_t ws_size,
                              hipStream_t stream) {
    const float* x = (const float*)d_in[0];
    const float* w_q = (const float*)d_in[1];
    const float* w_kv = (const float*)d_in[2];
    const float* w_out = (const float*)d_in[3];
    const float* b_out = (const float*)d_in[4];
    float* out = (float*)d_out;

    char* ws = (char*)d_ws;
    size_t off = 0;
    auto alloc = [&](size_t bytes) -> char* {
        char* p = ws + off;
        off = (off + bytes + 255) & ~(size_t)255;
        return p;
    };
    u16* xp = (u16*)alloc(14450688ull * 2);     // x, patch order, bf16 [1152][12544]
    u16* wkvT = (u16*)alloc(12845056ull * 2);   // [1024][12544]
    u16* wqT = (u16*)alloc(131072ull * 2);      // [512][256], pre-scaled by 0.125
    u16* woutT = (u16*)alloc(131072ull * 2);    // [256][512]
    u16* Kb = (u16*)alloc(1179648ull);          // [64][144][64] bf16
    u16* Vt = (u16*)alloc(1310720ull);          // [64][64][160] bf16 (pad cols never read)
    u16* O = (u16*)alloc(57802752ull);          // [56448][512] bf16
    float* parts = (float*)alloc(33030144ull);  // [7][1152][1024] fp32
    u16* Qb = (u16*)parts;                      // overlay: [64][7056][64] bf16 (parts dead after k_kvfin)

    k_pack_x<<<7056, 256, 0, stream>>>(x, xp);
    k_tconv<<<dim3(32, 392), dim3(32, 8), 0, stream>>>(w_kv, wkvT, 12544, 1024, 1.0f);
    k_tconv<<<dim3(16, 8), dim3(32, 8), 0, stream>>>(w_q, wqT, 256, 512, 0.125f);
    k_tconv<<<dim3(8, 16), dim3(32, 8), 0, stream>>>(w_out, woutT, 512, 256, 1.0f);
    k_kvproj<<<dim3(9, 8, 7), 256, 0, stream>>>(xp, wkvT, parts);
    k_kvfin<<<4608, 256, 0, stream>>>(parts, Kb, Vt);
    k_qproj<<<dim3(441, 4), 256, 0, stream>>>(xp, wqT, Qb);
    k_attn<<<dim3(441, 8, 8), 64, 0, stream>>>(Qb, Kb, Vt, O);
    k_outproj<<<dim3(441, 2), 256, 0, stream>>>(O, woutT, b_out, out);
}